// Round 11
// baseline (888.044 us; speedup 1.0000x reference)
//
#include <hip/hip_runtime.h>

// Problem constants
#define BB 16
#define CC 256
#define CH 128
#define HH 128
#define WW 128
#define HW (HH*WW)
#define KPOOL 11
#define PADP 5
#define EPS 1e-5f

typedef __attribute__((ext_vector_type(8))) short s16x8;
typedef __attribute__((ext_vector_type(4))) float f32x4;
typedef __attribute__((ext_vector_type(8))) unsigned short u16x8;
typedef __attribute__((ext_vector_type(4))) unsigned short u16x4;
typedef __attribute__((ext_vector_type(4))) unsigned int u32x4;

static __device__ __forceinline__ unsigned short f2bf(float f) {
    unsigned int u = __float_as_uint(f);
    u = u + 0x7fffu + ((u >> 16) & 1u);   // RNE
    return (unsigned short)(u >> 16);
}
static __device__ __forceinline__ float bf2f(unsigned short h) {
    return __uint_as_float(((unsigned int)h) << 16);
}

#define MFMA16(a, b, c) __builtin_amdgcn_mfma_f32_16x16x32_bf16((a), (b), (c), 0, 0, 0)

// ---------------------------------------------------------------------------
// Kernel 0: prep — split weights into bf16 hi/lo pairs, fold BN into (scale,shift)
// ---------------------------------------------------------------------------
__global__ __launch_bounds__(256) void prep_kernel(
    const float* __restrict__ w1, const float* __restrict__ b1,
    const float* __restrict__ g1, const float* __restrict__ be1,
    const float* __restrict__ m1, const float* __restrict__ v1,
    const float* __restrict__ w2, const float* __restrict__ b2,
    const float* __restrict__ g2, const float* __restrict__ be2,
    const float* __restrict__ m2, const float* __restrict__ v2,
    unsigned short* __restrict__ w1h, unsigned short* __restrict__ w1l,
    unsigned short* __restrict__ w2h, unsigned short* __restrict__ w2l,
    float* __restrict__ A1, float* __restrict__ B1,
    float* __restrict__ A2, float* __restrict__ B2)
{
    int i = blockIdx.x * 256 + threadIdx.x;   // grid covers 32768
    if (i < CH * CC) {
        float w = w1[i];
        unsigned short hi = f2bf(w);
        w1h[i] = hi;
        w1l[i] = f2bf(w - bf2f(hi));
        float u = w2[i];
        unsigned short hi2 = f2bf(u);
        w2h[i] = hi2;
        w2l[i] = f2bf(u - bf2f(hi2));
    }
    if (i < CH) {
        float sc = g1[i] * rsqrtf(v1[i] + EPS);
        A1[i] = sc;
        B1[i] = be1[i] + (b1[i] - m1[i]) * sc;
    }
    if (i < CC) {
        float sc = g2[i] * rsqrtf(v2[i] + EPS);
        A2[i] = sc;
        B2[i] = be2[i] + (b2[i] - m2[i]) * sc;
    }
}

// ---------------------------------------------------------------------------
// Kernel 1: edge = x - boxavg11(x). O(1) taps/output:
//   vertical 11-tap via per-column running sums (2 LDS reads/output),
//   horizontal 11-tap via per-row wave prefix scan (2 LDS reads/output).
// Zero-pad semantics: halo rows zero-filled; horizontal uses clamped prefix
// bounds (values outside [0,128) contribute 0). /121 always.
// LDS = 13 + 8 + 8.25 KB = 29.25 KB -> 5 blocks/CU.
// ---------------------------------------------------------------------------
__global__ __launch_bounds__(256) void box_edge_kernel(
    const float* __restrict__ x, unsigned short* __restrict__ edge)
{
    constexpr int RB = 16;                 // rows per block
    int blk  = blockIdx.x;
    int band = blk & 7;                    // H/RB = 8 bands
    int bc   = blk >> 3;                   // b*C + c
    const float* img = x + (size_t)bc * HW;

    __shared__ float tile[RB + 2*PADP][WW];  // 26*128*4 = 13 KB
    __shared__ float vs[RB][WW];             //  8 KB vertical sums
    __shared__ float P[RB][WW + 4];          //  8.25 KB horizontal prefix

    int h0 = band * RB;
    int t  = threadIdx.x;

    // load rows [h0-5, h0+RB+5) as float4, zero outside image
    for (int idx = t; idx < (RB + 2*PADP) * (WW/4); idx += 256) {
        int r  = idx >> 5;
        int w4 = idx & 31;
        int h  = h0 - PADP + r;
        f32x4 v = {0.f, 0.f, 0.f, 0.f};
        if (h >= 0 && h < HH) v = *(const f32x4*)(img + h * WW + w4 * 4);
        *(f32x4*)&tile[r][w4 * 4] = v;
    }
    __syncthreads();

    // vertical running sums: thread = (w, half), 8 outputs each
    {
        int w = t & 127, half = t >> 7;
        int r0 = half * 8;
        float s = 0.f;
#pragma unroll
        for (int j = 0; j < KPOOL; ++j) s += tile[r0 + j][w];
        vs[r0][w] = s;
#pragma unroll
        for (int k = 1; k < 8; ++k) {
            s += tile[r0 + 10 + k][w] - tile[r0 + k - 1][w];
            vs[r0 + k][w] = s;
        }
    }
    __syncthreads();

    // horizontal prefix per row: wave wv handles rows 4wv..4wv+3
    {
        int lane = t & 63, wv = t >> 6;
#pragma unroll
        for (int rr = 0; rr < 4; ++rr) {
            int r = wv * 4 + rr;
            float v = vs[r][lane];                      // chunk 0
#pragma unroll
            for (int d = 1; d < 64; d <<= 1) {
                float u = __shfl_up(v, d, 64);
                if (lane >= d) v += u;
            }
            P[r][lane + 1] = v;
            float carry = __shfl(v, 63, 64);
            float v2 = vs[r][64 + lane];                // chunk 1
#pragma unroll
            for (int d = 1; d < 64; d <<= 1) {
                float u = __shfl_up(v2, d, 64);
                if (lane >= d) v2 += u;
            }
            P[r][65 + lane] = v2 + carry;
            if (lane == 0) P[r][0] = 0.f;
        }
    }
    __syncthreads();

    // outputs: box sum = P[min(w+5,127)+1] - P[max(w-5,0)]
    for (int idx = t; idx < RB * WW; idx += 256) {
        int r = idx >> 7, w = idx & 127;
        int a = w - 5; if (a < 0) a = 0;
        int bq = w + 6; if (bq > 128) bq = 128;
        float s = P[r][bq] - P[r][a];
        float e = tile[r + PADP][w] - s * (1.f / (KPOOL * KPOOL));
        edge[(size_t)bc * HW + (size_t)(h0 + r) * WW + w] = f2bf(e);
    }
}

// ---------------------------------------------------------------------------
// Kernel 2: transpose edge [b][c][p] -> edge_t [b][p][c]  (R5-measured, unchanged)
// ---------------------------------------------------------------------------
__global__ __launch_bounds__(256) void transpose_kernel(
    const unsigned short* __restrict__ edge_raw, unsigned short* __restrict__ edge_t)
{
    int blk = blockIdx.x;                 // grid = B * (HW/64) * (C/64) = 16384
    int c0 = (blk & 3) * 64;
    int p0 = ((blk >> 2) & 255) * 64;
    int b  = blk >> 10;

    __shared__ unsigned int lds32[64 * 33];  // 8.25 KB

    int t  = threadIdx.x;
    int rp = t >> 3;                      // row-pair 0..31 (c = 2rp, 2rp+1)
    int sl = t & 7;                       // 16B p-slot 0..7

    size_t rowA = ((size_t)(b * CC + c0 + 2 * rp)) << 14;
    u16x8 a = *(const u16x8*)(edge_raw + rowA + p0 + sl * 8);
    u16x8 c = *(const u16x8*)(edge_raw + rowA + (1 << 14) + p0 + sl * 8);

#pragma unroll
    for (int j = 0; j < 8; ++j) {
        unsigned int w = (unsigned int)a[j] | ((unsigned int)c[j] << 16);
        lds32[(sl * 8 + j) * 33 + rp] = w;   // [p_local][c_pair]
    }
    __syncthreads();

    int p = t >> 2;                       // p_local 0..63
    int q = t & 3;                        // 16-c chunk 0..3
    u32x4 o0, o1;
#pragma unroll
    for (int k = 0; k < 4; ++k) o0[k] = lds32[p * 33 + q * 8 + k];
#pragma unroll
    for (int k = 0; k < 4; ++k) o1[k] = lds32[p * 33 + q * 8 + 4 + k];

    unsigned short* dst = edge_t + (((size_t)(b * HW + p0 + p)) << 8) + c0 + q * 16;
    *(u32x4*)dst       = o0;
    *(u32x4*)(dst + 8) = o1;
}

// ---------------------------------------------------------------------------
// Kernel 3 (fused GEMM1+GEMM2), 8-wave, no eT staging:
//   Phase A: wave computes 16 o over K=256; edge fragments read DIRECTLY from
//            global (all 8 waves share the 32KB tile -> L1/L2-served).
//   Phase B: wave computes 32 o over K=128 from swizzled hT LDS.
// LDS = 16 KB only -> LDS no longer caps occupancy; (512,6) -> 24 waves/CU.
// ---------------------------------------------------------------------------
__global__ __launch_bounds__(512, 6) void gemm12_fused(
    const unsigned short* __restrict__ edge_t,
    const unsigned short* __restrict__ w1h, const unsigned short* __restrict__ w1l,
    const float* __restrict__ A1, const float* __restrict__ B1,
    const unsigned short* __restrict__ w2h, const unsigned short* __restrict__ w2l,
    const float* __restrict__ A2, const float* __restrict__ B2,
    const float* __restrict__ x, float* __restrict__ out)
{
    const int blk  = blockIdx.x;          // grid = B * (HW/64) = 4096
    const int b    = blk >> 8;
    const int p0   = (blk & 255) * 64;
    const int tid  = threadIdx.x;
    const int lane = tid & 63;
    const int l15  = lane & 15;
    const int l4   = lane >> 4;
    const int wv   = tid >> 6;            // wave id 0..7

    __shared__ unsigned short hT[64 * 128];   // 16 KB, XOR-swizzled 16B slots

    const unsigned short* E = edge_t + (((size_t)(b * HW + p0)) << 8);

    const f32x4 z4 = {0.f, 0.f, 0.f, 0.f};

    // ================= Phase A: GEMM1 (wave's 16 o, K=256) ===================
    {
        const int o = wv * 16 + l15;      // this lane's A-operand row
        f32x4 acc[4];
#pragma unroll
        for (int fp = 0; fp < 4; ++fp) acc[fp] = z4;

#pragma unroll
        for (int ks = 0; ks < 8; ++ks) {
            s16x8 bfr[4];
#pragma unroll
            for (int fp = 0; fp < 4; ++fp) {
                int pl = fp * 16 + l15;
                bfr[fp] = *(const s16x8*)(E + ((size_t)pl << 8) + ks * 32 + l4 * 8);
            }
            size_t wo = (size_t)o * CC + ks * 32 + l4 * 8;
            s16x8 ah = *(const s16x8*)(w1h + wo);
            s16x8 al = *(const s16x8*)(w1l + wo);
#pragma unroll
            for (int fp = 0; fp < 4; ++fp) {
                acc[fp] = MFMA16(ah, bfr[fp], acc[fp]);
                acc[fp] = MFMA16(al, bfr[fp], acc[fp]);
            }
        }

        // epilogue 1: BN + ReLU -> bf16 into hT with phase-B read swizzle.
        int ob = wv * 16 + l4 * 4;        // 4 consecutive channels; ob%8 in {0,4}
        f32x4 sc = *(const f32x4*)(A1 + ob);
        f32x4 sh = *(const f32x4*)(B1 + ob);
#pragma unroll
        for (int fp = 0; fp < 4; ++fp) {
            int pl = fp * 16 + l15;
            u16x4 hv;
#pragma unroll
            for (int r = 0; r < 4; ++r) {
                float v = acc[fp][r] * sc[r] + sh[r];
                v = fmaxf(v, 0.f);
                hv[r] = f2bf(v);
            }
            *(u16x4*)&hT[pl * 128 + ((ob >> 3) ^ (pl & 7)) * 8 + (ob & 7)] = hv;
        }
    }
    __syncthreads();

    // ================= Phase B: GEMM2 (wave's 32 o, K=128) ===================
    {
        const int o0 = wv * 32;
        f32x4 acc[2][4];
#pragma unroll
        for (int fo = 0; fo < 2; ++fo)
#pragma unroll
            for (int fp = 0; fp < 4; ++fp) acc[fo][fp] = z4;

#pragma unroll
        for (int ks = 0; ks < 4; ++ks) {
            s16x8 bfr[4];
#pragma unroll
            for (int fp = 0; fp < 4; ++fp) {
                int pl = fp * 16 + l15;
                bfr[fp] = *(const s16x8*)&hT[pl * 128 + ((ks * 4 + l4) ^ (pl & 7)) * 8];
            }
#pragma unroll
            for (int fo = 0; fo < 2; ++fo) {
                int o = o0 + fo * 16 + l15;
                size_t wo = (size_t)o * CH + ks * 32 + l4 * 8;
                s16x8 ah = *(const s16x8*)(w2h + wo);
                s16x8 al = *(const s16x8*)(w2l + wo);
#pragma unroll
                for (int fp = 0; fp < 4; ++fp) {
                    acc[fo][fp] = MFMA16(ah, bfr[fp], acc[fo][fp]);
                    acc[fo][fp] = MFMA16(al, bfr[fp], acc[fo][fp]);
                }
            }
        }

        // epilogue 2: BN + sigmoid + gated residual
#pragma unroll
        for (int fo = 0; fo < 2; ++fo) {
            int ob = o0 + fo * 16 + l4 * 4;
            f32x4 sc = *(const f32x4*)(A2 + ob);
            f32x4 sh = *(const f32x4*)(B2 + ob);
#pragma unroll
            for (int fp = 0; fp < 4; ++fp) {
                int p = p0 + fp * 16 + l15;
#pragma unroll
                for (int r = 0; r < 4; ++r) {
                    float z = acc[fo][fp][r] * sc[r] + sh[r];
                    float gte = 1.f / (1.f + __expf(-z));
                    size_t idx = (((size_t)(b * CC + ob + r)) << 14) + p;
                    out[idx] = x[idx] * (1.f + gte);
                }
            }
        }
    }
}

// ---------------------------------------------------------------------------
extern "C" void kernel_launch(void* const* d_in, const int* in_sizes, int n_in,
                              void* d_out, int out_size, void* d_ws, size_t ws_size,
                              hipStream_t stream) {
    const float* x   = (const float*)d_in[0];
    const float* w1  = (const float*)d_in[1];
    const float* b1  = (const float*)d_in[2];
    const float* g1  = (const float*)d_in[3];
    const float* be1 = (const float*)d_in[4];
    const float* m1  = (const float*)d_in[5];
    const float* v1  = (const float*)d_in[6];
    const float* w2  = (const float*)d_in[7];
    const float* b2  = (const float*)d_in[8];
    const float* g2  = (const float*)d_in[9];
    const float* be2 = (const float*)d_in[10];
    const float* m2  = (const float*)d_in[11];
    const float* v2  = (const float*)d_in[12];
    float* out = (float*)d_out;

    const size_t EDGE_BYTES  = (size_t)BB * CC * HW * 2;  // 128 MiB
    const size_t SMALL_BYTES = 4 * (size_t)CH * CC * 2 + (2 * CH + 2 * CC) * 4;

    // edge_raw always lives in d_out[0,128MiB): d_out is written (as output) only
    // by the final kernel, after both edge buffers are dead.
    unsigned short* edge_raw = (unsigned short*)d_out;
    unsigned short* edge_t;
    char* smalls;
    if (ws_size >= EDGE_BYTES + SMALL_BYTES) {
        edge_t = (unsigned short*)d_ws;
        smalls = (char*)d_ws + EDGE_BYTES;
    } else {
        edge_t = (unsigned short*)((char*)d_out + EDGE_BYTES);  // d_out[128,256MiB)
        smalls = (char*)d_ws;                                    // needs ~256 KB
    }
    unsigned short* w1h = (unsigned short*)smalls;
    unsigned short* w1l = w1h + CH * CC;
    unsigned short* w2h = w1l + CH * CC;
    unsigned short* w2l = w2h + CH * CC;
    float* A1v = (float*)(w2l + CH * CC);
    float* B1v = A1v + CH;
    float* A2v = B1v + CH;
    float* B2v = A2v + CC;

    // K0: weight split + BN fold
    prep_kernel<<<128, 256, 0, stream>>>(w1, b1, g1, be1, m1, v1,
                                         w2, b2, g2, be2, m2, v2,
                                         w1h, w1l, w2h, w2l, A1v, B1v, A2v, B2v);

    // K1: box filter + edge (bf16, [c][p])
    box_edge_kernel<<<BB * CC * (HH / 16), 256, 0, stream>>>(x, edge_raw);

    // K2: transpose to [p][c]
    transpose_kernel<<<BB * (HW / 64) * (CC / 64), 256, 0, stream>>>(edge_raw, edge_t);

    // K3: fused conv1+BN+ReLU -> conv2+BN+sigmoid -> gated residual
    gemm12_fused<<<BB * (HW / 64), 512, 0, stream>>>(
        edge_t, w1h, w1l, A1v, B1v, w2h, w2l, A2v, B2v, x, out);
}

// Round 12
// 770.571 us; speedup vs baseline: 1.1524x; 1.1524x over previous
//
#include <hip/hip_runtime.h>

// Problem constants
#define BB 16
#define CC 256
#define CH 128
#define HH 128
#define WW 128
#define HW (HH*WW)
#define KPOOL 11
#define PADP 5
#define EPS 1e-5f

typedef __attribute__((ext_vector_type(8))) short s16x8;
typedef __attribute__((ext_vector_type(4))) float f32x4;
typedef __attribute__((ext_vector_type(8))) unsigned short u16x8;
typedef __attribute__((ext_vector_type(4))) unsigned short u16x4;
typedef __attribute__((ext_vector_type(4))) unsigned int u32x4;

static __device__ __forceinline__ unsigned short f2bf(float f) {
    unsigned int u = __float_as_uint(f);
    u = u + 0x7fffu + ((u >> 16) & 1u);   // RNE
    return (unsigned short)(u >> 16);
}
static __device__ __forceinline__ float bf2f(unsigned short h) {
    return __uint_as_float(((unsigned int)h) << 16);
}

#define MFMA16(a, b, c) __builtin_amdgcn_mfma_f32_16x16x32_bf16((a), (b), (c), 0, 0, 0)

// ---------------------------------------------------------------------------
// Kernel 0: prep — split weights into bf16 hi/lo pairs, fold BN into (scale,shift)
// ---------------------------------------------------------------------------
__global__ __launch_bounds__(256) void prep_kernel(
    const float* __restrict__ w1, const float* __restrict__ b1,
    const float* __restrict__ g1, const float* __restrict__ be1,
    const float* __restrict__ m1, const float* __restrict__ v1,
    const float* __restrict__ w2, const float* __restrict__ b2,
    const float* __restrict__ g2, const float* __restrict__ be2,
    const float* __restrict__ m2, const float* __restrict__ v2,
    unsigned short* __restrict__ w1h, unsigned short* __restrict__ w1l,
    unsigned short* __restrict__ w2h, unsigned short* __restrict__ w2l,
    float* __restrict__ A1, float* __restrict__ B1,
    float* __restrict__ A2, float* __restrict__ B2)
{
    int i = blockIdx.x * 256 + threadIdx.x;   // grid covers 32768
    if (i < CH * CC) {
        float w = w1[i];
        unsigned short hi = f2bf(w);
        w1h[i] = hi;
        w1l[i] = f2bf(w - bf2f(hi));
        float u = w2[i];
        unsigned short hi2 = f2bf(u);
        w2h[i] = hi2;
        w2l[i] = f2bf(u - bf2f(hi2));
    }
    if (i < CH) {
        float sc = g1[i] * rsqrtf(v1[i] + EPS);
        A1[i] = sc;
        B1[i] = be1[i] + (b1[i] - m1[i]) * sc;
    }
    if (i < CC) {
        float sc = g2[i] * rsqrtf(v2[i] + EPS);
        A2[i] = sc;
        B2[i] = be2[i] + (b2[i] - m2[i]) * sc;
    }
}

// ---------------------------------------------------------------------------
// Kernel 1: edge = x - boxavg11(x). O(1) taps/output (R11-measured, unchanged)
// ---------------------------------------------------------------------------
__global__ __launch_bounds__(256) void box_edge_kernel(
    const float* __restrict__ x, unsigned short* __restrict__ edge)
{
    constexpr int RB = 16;                 // rows per block
    int blk  = blockIdx.x;
    int band = blk & 7;                    // H/RB = 8 bands
    int bc   = blk >> 3;                   // b*C + c
    const float* img = x + (size_t)bc * HW;

    __shared__ float tile[RB + 2*PADP][WW];  // 13 KB
    __shared__ float vs[RB][WW];             //  8 KB vertical sums
    __shared__ float P[RB][WW + 4];          //  8.25 KB horizontal prefix

    int h0 = band * RB;
    int t  = threadIdx.x;

    for (int idx = t; idx < (RB + 2*PADP) * (WW/4); idx += 256) {
        int r  = idx >> 5;
        int w4 = idx & 31;
        int h  = h0 - PADP + r;
        f32x4 v = {0.f, 0.f, 0.f, 0.f};
        if (h >= 0 && h < HH) v = *(const f32x4*)(img + h * WW + w4 * 4);
        *(f32x4*)&tile[r][w4 * 4] = v;
    }
    __syncthreads();

    {
        int w = t & 127, half = t >> 7;
        int r0 = half * 8;
        float s = 0.f;
#pragma unroll
        for (int j = 0; j < KPOOL; ++j) s += tile[r0 + j][w];
        vs[r0][w] = s;
#pragma unroll
        for (int k = 1; k < 8; ++k) {
            s += tile[r0 + 10 + k][w] - tile[r0 + k - 1][w];
            vs[r0 + k][w] = s;
        }
    }
    __syncthreads();

    {
        int lane = t & 63, wv = t >> 6;
#pragma unroll
        for (int rr = 0; rr < 4; ++rr) {
            int r = wv * 4 + rr;
            float v = vs[r][lane];                      // chunk 0
#pragma unroll
            for (int d = 1; d < 64; d <<= 1) {
                float u = __shfl_up(v, d, 64);
                if (lane >= d) v += u;
            }
            P[r][lane + 1] = v;
            float carry = __shfl(v, 63, 64);
            float v2 = vs[r][64 + lane];                // chunk 1
#pragma unroll
            for (int d = 1; d < 64; d <<= 1) {
                float u = __shfl_up(v2, d, 64);
                if (lane >= d) v2 += u;
            }
            P[r][65 + lane] = v2 + carry;
            if (lane == 0) P[r][0] = 0.f;
        }
    }
    __syncthreads();

    for (int idx = t; idx < RB * WW; idx += 256) {
        int r = idx >> 7, w = idx & 127;
        int a = w - 5; if (a < 0) a = 0;
        int bq = w + 6; if (bq > 128) bq = 128;
        float s = P[r][bq] - P[r][a];
        float e = tile[r + PADP][w] - s * (1.f / (KPOOL * KPOOL));
        edge[(size_t)bc * HW + (size_t)(h0 + r) * WW + w] = f2bf(e);
    }
}

// ---------------------------------------------------------------------------
// Kernel 2: transpose edge [b][c][p] -> edge_t [b][p][c]  (measured, unchanged)
// ---------------------------------------------------------------------------
__global__ __launch_bounds__(256) void transpose_kernel(
    const unsigned short* __restrict__ edge_raw, unsigned short* __restrict__ edge_t)
{
    int blk = blockIdx.x;                 // grid = B * (HW/64) * (C/64) = 16384
    int c0 = (blk & 3) * 64;
    int p0 = ((blk >> 2) & 255) * 64;
    int b  = blk >> 10;

    __shared__ unsigned int lds32[64 * 33];  // 8.25 KB

    int t  = threadIdx.x;
    int rp = t >> 3;                      // row-pair 0..31 (c = 2rp, 2rp+1)
    int sl = t & 7;                       // 16B p-slot 0..7

    size_t rowA = ((size_t)(b * CC + c0 + 2 * rp)) << 14;
    u16x8 a = *(const u16x8*)(edge_raw + rowA + p0 + sl * 8);
    u16x8 c = *(const u16x8*)(edge_raw + rowA + (1 << 14) + p0 + sl * 8);

#pragma unroll
    for (int j = 0; j < 8; ++j) {
        unsigned int w = (unsigned int)a[j] | ((unsigned int)c[j] << 16);
        lds32[(sl * 8 + j) * 33 + rp] = w;   // [p_local][c_pair]
    }
    __syncthreads();

    int p = t >> 2;                       // p_local 0..63
    int q = t & 3;                        // 16-c chunk 0..3
    u32x4 o0, o1;
#pragma unroll
    for (int k = 0; k < 4; ++k) o0[k] = lds32[p * 33 + q * 8 + k];
#pragma unroll
    for (int k = 0; k < 4; ++k) o1[k] = lds32[p * 33 + q * 8 + 4 + k];

    unsigned short* dst = edge_t + (((size_t)(b * HW + p0 + p)) << 8) + c0 + q * 16;
    *(u32x4*)dst       = o0;
    *(u32x4*)(dst + 8) = o1;
}

// ---------------------------------------------------------------------------
// Kernel 3 (fused GEMM1+GEMM2), R7-measured structure (eT+hT staged LDS,
// 8 waves) + two latency hoists:
//   - weight register double-buffer (issue ks+1 loads before ks MFMAs)
//   - epilogue-2 x values prefetched into registers at phase-B start
// LDS = 32KB eT + 16KB hT = 48KB -> 3 blocks/CU = 24 waves/CU.
// ---------------------------------------------------------------------------
__global__ __launch_bounds__(512, 6) void gemm12_fused(
    const unsigned short* __restrict__ edge_t,
    const unsigned short* __restrict__ w1h, const unsigned short* __restrict__ w1l,
    const float* __restrict__ A1, const float* __restrict__ B1,
    const unsigned short* __restrict__ w2h, const unsigned short* __restrict__ w2l,
    const float* __restrict__ A2, const float* __restrict__ B2,
    const float* __restrict__ x, float* __restrict__ out)
{
    const int blk  = blockIdx.x;          // grid = B * (HW/64) = 4096
    const int b    = blk >> 8;
    const int p0   = (blk & 255) * 64;
    const int tid  = threadIdx.x;
    const int lane = tid & 63;
    const int l15  = lane & 15;
    const int l4   = lane >> 4;
    const int wv   = tid >> 6;            // wave id 0..7

    __shared__ unsigned short eT[64 * 256];   // 32 KB, XOR-swizzled 16B slots
    __shared__ unsigned short hT[64 * 128];   // 16 KB, XOR-swizzled 16B slots

    const unsigned short* E = edge_t + (((size_t)(b * HW + p0)) << 8);

    // ---- stage eT (swizzled store; read recovers with same XOR) ----
#pragma unroll
    for (int i = 0; i < 4; ++i) {
        int L  = i * 512 + tid;           // linear 16B-slot index 0..2047
        int pl = L >> 5;
        int s  = L & 31;
        int g  = s ^ (pl & 7);            // inverse-swizzled source slot
        *(u16x8*)&eT[pl * 256 + s * 8] = *(const u16x8*)(E + pl * 256 + g * 8);
    }
    __syncthreads();

    const f32x4 z4 = {0.f, 0.f, 0.f, 0.f};

    // ================= Phase A: GEMM1 (wave's 16 o, K=256) ===================
    {
        const int o = wv * 16 + l15;      // this lane's A-operand row
        const unsigned short* W1h = w1h + (size_t)o * CC;
        const unsigned short* W1l = w1l + (size_t)o * CC;

        f32x4 acc[4];
#pragma unroll
        for (int fp = 0; fp < 4; ++fp) acc[fp] = z4;

        s16x8 ah = *(const s16x8*)(W1h + l4 * 8);
        s16x8 al = *(const s16x8*)(W1l + l4 * 8);

#pragma unroll
        for (int ks = 0; ks < 8; ++ks) {
            s16x8 ah_n, al_n;
            if (ks < 7) {                 // prefetch next-ks weights
                ah_n = *(const s16x8*)(W1h + (ks + 1) * 32 + l4 * 8);
                al_n = *(const s16x8*)(W1l + (ks + 1) * 32 + l4 * 8);
            }
            s16x8 bfr[4];
#pragma unroll
            for (int fp = 0; fp < 4; ++fp) {
                int pl = fp * 16 + l15;
                bfr[fp] = *(const s16x8*)&eT[pl * 256 + ((ks * 4 + l4) ^ (pl & 7)) * 8];
            }
#pragma unroll
            for (int fp = 0; fp < 4; ++fp) {
                acc[fp] = MFMA16(ah, bfr[fp], acc[fp]);
                acc[fp] = MFMA16(al, bfr[fp], acc[fp]);
            }
            ah = ah_n; al = al_n;
        }

        // epilogue 1: BN + ReLU -> bf16 into hT with phase-B read swizzle.
        int ob = wv * 16 + l4 * 4;        // 4 consecutive channels; ob%8 in {0,4}
        f32x4 sc = *(const f32x4*)(A1 + ob);
        f32x4 sh = *(const f32x4*)(B1 + ob);
#pragma unroll
        for (int fp = 0; fp < 4; ++fp) {
            int pl = fp * 16 + l15;
            u16x4 hv;
#pragma unroll
            for (int r = 0; r < 4; ++r) {
                float v = acc[fp][r] * sc[r] + sh[r];
                v = fmaxf(v, 0.f);
                hv[r] = f2bf(v);
            }
            *(u16x4*)&hT[pl * 128 + ((ob >> 3) ^ (pl & 7)) * 8 + (ob & 7)] = hv;
        }
    }
    __syncthreads();

    // ================= Phase B: GEMM2 (wave's 32 o, K=128) ===================
    {
        const int o0 = wv * 32;

        // prefetch the 32 epilogue x values NOW (after the barrier's vmcnt
        // drain) so their ~HBM latency hides under the MFMA stream below.
        float xv[2][4][4];
#pragma unroll
        for (int fo = 0; fo < 2; ++fo) {
            int ob = o0 + fo * 16 + l4 * 4;
#pragma unroll
            for (int fp = 0; fp < 4; ++fp) {
                int p = p0 + fp * 16 + l15;
#pragma unroll
                for (int r = 0; r < 4; ++r)
                    xv[fo][fp][r] = x[(((size_t)(b * CC + ob + r)) << 14) + p];
            }
        }

        f32x4 acc[2][4];
#pragma unroll
        for (int fo = 0; fo < 2; ++fo)
#pragma unroll
            for (int fp = 0; fp < 4; ++fp) acc[fo][fp] = z4;

#pragma unroll
        for (int ks = 0; ks < 4; ++ks) {
            s16x8 bfr[4];
#pragma unroll
            for (int fp = 0; fp < 4; ++fp) {
                int pl = fp * 16 + l15;
                bfr[fp] = *(const s16x8*)&hT[pl * 128 + ((ks * 4 + l4) ^ (pl & 7)) * 8];
            }
#pragma unroll
            for (int fo = 0; fo < 2; ++fo) {
                int o = o0 + fo * 16 + l15;
                size_t wo = (size_t)o * CH + ks * 32 + l4 * 8;
                s16x8 ah = *(const s16x8*)(w2h + wo);
                s16x8 al = *(const s16x8*)(w2l + wo);
#pragma unroll
                for (int fp = 0; fp < 4; ++fp) {
                    acc[fo][fp] = MFMA16(ah, bfr[fp], acc[fo][fp]);
                    acc[fo][fp] = MFMA16(al, bfr[fp], acc[fo][fp]);
                }
            }
        }

        // epilogue 2: BN + sigmoid + gated residual (x already in registers)
#pragma unroll
        for (int fo = 0; fo < 2; ++fo) {
            int ob = o0 + fo * 16 + l4 * 4;
            f32x4 sc = *(const f32x4*)(A2 + ob);
            f32x4 sh = *(const f32x4*)(B2 + ob);
#pragma unroll
            for (int fp = 0; fp < 4; ++fp) {
                int p = p0 + fp * 16 + l15;
#pragma unroll
                for (int r = 0; r < 4; ++r) {
                    float z = acc[fo][fp][r] * sc[r] + sh[r];
                    float gte = 1.f / (1.f + __expf(-z));
                    size_t idx = (((size_t)(b * CC + ob + r)) << 14) + p;
                    out[idx] = xv[fo][fp][r] * (1.f + gte);
                }
            }
        }
    }
}

// ---------------------------------------------------------------------------
extern "C" void kernel_launch(void* const* d_in, const int* in_sizes, int n_in,
                              void* d_out, int out_size, void* d_ws, size_t ws_size,
                              hipStream_t stream) {
    const float* x   = (const float*)d_in[0];
    const float* w1  = (const float*)d_in[1];
    const float* b1  = (const float*)d_in[2];
    const float* g1  = (const float*)d_in[3];
    const float* be1 = (const float*)d_in[4];
    const float* m1  = (const float*)d_in[5];
    const float* v1  = (const float*)d_in[6];
    const float* w2  = (const float*)d_in[7];
    const float* b2  = (const float*)d_in[8];
    const float* g2  = (const float*)d_in[9];
    const float* be2 = (const float*)d_in[10];
    const float* m2  = (const float*)d_in[11];
    const float* v2  = (const float*)d_in[12];
    float* out = (float*)d_out;

    const size_t EDGE_BYTES  = (size_t)BB * CC * HW * 2;  // 128 MiB
    const size_t SMALL_BYTES = 4 * (size_t)CH * CC * 2 + (2 * CH + 2 * CC) * 4;

    // edge_raw always lives in d_out[0,128MiB): d_out is written (as output) only
    // by the final kernel, after both edge buffers are dead.
    unsigned short* edge_raw = (unsigned short*)d_out;
    unsigned short* edge_t;
    char* smalls;
    if (ws_size >= EDGE_BYTES + SMALL_BYTES) {
        edge_t = (unsigned short*)d_ws;
        smalls = (char*)d_ws + EDGE_BYTES;
    } else {
        edge_t = (unsigned short*)((char*)d_out + EDGE_BYTES);  // d_out[128,256MiB)
        smalls = (char*)d_ws;                                    // needs ~256 KB
    }
    unsigned short* w1h = (unsigned short*)smalls;
    unsigned short* w1l = w1h + CH * CC;
    unsigned short* w2h = w1l + CH * CC;
    unsigned short* w2l = w2h + CH * CC;
    float* A1v = (float*)(w2l + CH * CC);
    float* B1v = A1v + CH;
    float* A2v = B1v + CH;
    float* B2v = A2v + CC;

    // K0: weight split + BN fold
    prep_kernel<<<128, 256, 0, stream>>>(w1, b1, g1, be1, m1, v1,
                                         w2, b2, g2, be2, m2, v2,
                                         w1h, w1l, w2h, w2l, A1v, B1v, A2v, B2v);

    // K1: box filter + edge (bf16, [c][p])
    box_edge_kernel<<<BB * CC * (HH / 16), 256, 0, stream>>>(x, edge_raw);

    // K2: transpose to [p][c]
    transpose_kernel<<<BB * (HW / 64) * (CC / 64), 256, 0, stream>>>(edge_raw, edge_t);

    // K3: fused conv1+BN+ReLU -> conv2+BN+sigmoid -> gated residual
    gemm12_fused<<<BB * (HW / 64), 512, 0, stream>>>(
        edge_t, w1h, w1l, A1v, B1v, w2h, w2l, A2v, B2v, x, out);
}